// Round 2
// baseline (983.501 us; speedup 1.0000x reference)
//
#include <hip/hip_runtime.h>
#include <hip/hip_bf16.h>

typedef unsigned short u16;
typedef unsigned int   u32;
typedef __attribute__((ext_vector_type(4))) float f4v;
typedef __attribute__((ext_vector_type(8))) short s8v;

#define NB   32      // batch
#define NS   256     // src len
#define NT   8       // dec len
#define NH   512     // hidden
#define NENC 512
#define NEMB 256
#define NVOC 50000
#define NVT  51000

__device__ __forceinline__ float bf2f(u16 u){ return __uint_as_float(((u32)u)<<16); }
__device__ __forceinline__ u16 f2bf(float f){
  u32 x = __float_as_uint(f);
  return (u16)((x + 0x7fffu + ((x>>16)&1u)) >> 16);   // RNE
}
__device__ __forceinline__ s8v ld_frag(const u16* p){
  union{ s8v v; uint2 u[2]; } t;
  t.u[0] = *(const uint2*)p;
  t.u[1] = *(const uint2*)(p+4);
  return t.v;
}
__device__ __forceinline__ f4v mfma16(s8v a, s8v b, f4v c){
  return __builtin_amdgcn_mfma_f32_16x16x32_bf16(a,b,c,0,0,0);
}
__device__ __forceinline__ float sigm(float x){ return 1.f/(1.f+__expf(-x)); }

// ---------------------------------------------------------------------------
// Tiled bf16-MFMA GEMM: C[M,N] = epi(A[M,K] @ B[K,N])
//   A: fp32 (converted inline, optional row-gather) or bf16 direct
//   B: fp32 [K][N] staged via float4 loads, transposed to LDS [n][k] bf16
//   EPI 0: fp32 store   1: bf16 store of tanh(x+bias[n])
//   EPI 2: fp32 store of exp(x) for n<nlim + atomic per-row sums
//   MXA:  true -> m0 from blockIdx.x (m fastest), false -> m0 from blockIdx.y
// Block 256 threads = 4 waves (2x2), wave tile (BM/2)x(BN/2), 16x16x32 MFMA.
// ---------------------------------------------------------------------------
template<int BM, int BN, int EPI, bool ABF16, bool AGATHER, bool MXA>
__global__ __launch_bounds__(256)
void gemm_mfma(const void* __restrict__ Av, const float* __restrict__ B,
               float* __restrict__ C, const int* __restrict__ a_idx,
               const float* __restrict__ bias, float* __restrict__ rowsum,
               int K, int lda, int ldb, int ldc, int nlim)
{
  constexpr int LDT = 36;
  __shared__ u16 Al[BM*LDT];
  __shared__ u16 Bl[BN*LDT];
  const int tid  = threadIdx.x;
  const int lane = tid & 63;
  const int wave = tid >> 6;
  const int m0 = (MXA ? blockIdx.x : blockIdx.y) * BM;
  const int n0 = (MXA ? blockIdx.y : blockIdx.x) * BN;
  constexpr int TM = BM/32;
  constexpr int TN = BN/32;
  const int wm = (wave>>1)*(BM/2);
  const int wn = (wave&1)*(BN/2);
  const int q  = lane >> 4;
  const int ln = lane & 15;

  f4v acc[TM][TN];
  #pragma unroll
  for (int im=0; im<TM; ++im)
    #pragma unroll
    for (int in=0; in<TN; ++in) acc[im][in] = 0.f;

  const int KB = K >> 5;
  for (int kb=0; kb<KB; ++kb){
    __syncthreads();
    // ---- stage A tile [BM x 32] -> Al
    if (ABF16){
      const u16* Ag = (const u16*)Av;
      #pragma unroll
      for (int i=0; i<BM/64; ++i){
        int el = tid + i*256;
        int row = el>>2, ck = el&3;
        const u16* src = Ag + (size_t)(m0+row)*lda + kb*32 + ck*8;
        uint2 v0 = *(const uint2*)src;
        uint2 v1 = *(const uint2*)(src+4);
        u16* dst = &Al[row*LDT + ck*8];
        *(uint2*)dst = v0; *(uint2*)(dst+4) = v1;
      }
    } else {
      const float* Ag = (const float*)Av;
      #pragma unroll
      for (int i=0; i<BM/32; ++i){
        int el = tid + i*256;
        int row = el>>3, ck = el&7;
        int grow = AGATHER ? a_idx[m0+row] : (m0+row);
        f4v v = *(const f4v*)(Ag + (size_t)grow*lda + kb*32 + ck*4);
        uint2 p;
        p.x = (u32)f2bf(v.x) | ((u32)f2bf(v.y)<<16);
        p.y = (u32)f2bf(v.z) | ((u32)f2bf(v.w)<<16);
        *(uint2*)&Al[row*LDT + ck*4] = p;
      }
    }
    // ---- stage B tile [32 x BN] fp32 via float4, transpose -> Bl[n][k]
    {
      constexpr int NL  = BN/4;     // float4 chunks per k-row
      constexpr int KP2 = 256/NL;   // k rows covered per pass
      const int n4 = tid & (NL-1);
      const int kk = tid / NL;
      #pragma unroll
      for (int p=0; p<32/KP2; ++p){
        int k = kk + p*KP2;
        int n = n0 + n4*4;
        int ns = (n+4 <= nlim) ? n : (nlim-4);   // nlim multiple of 4
        f4v v = *(const f4v*)(B + (size_t)(kb*32+k)*ldb + ns);
        Bl[(n4*4+0)*LDT + k] = f2bf(v.x);
        Bl[(n4*4+1)*LDT + k] = f2bf(v.y);
        Bl[(n4*4+2)*LDT + k] = f2bf(v.z);
        Bl[(n4*4+3)*LDT + k] = f2bf(v.w);
      }
    }
    __syncthreads();
    // ---- fragments + MFMA
    s8v af[TM], bfr[TN];
    #pragma unroll
    for (int im=0; im<TM; ++im)
      af[im] = ld_frag(&Al[(wm+im*16+ln)*LDT + q*8]);
    #pragma unroll
    for (int in=0; in<TN; ++in)
      bfr[in] = ld_frag(&Bl[(wn+in*16+ln)*LDT + q*8]);
    #pragma unroll
    for (int im=0; im<TM; ++im)
      #pragma unroll
      for (int in=0; in<TN; ++in)
        acc[im][in] = mfma16(af[im], bfr[in], acc[im][in]);
  }

  // ---- epilogue. C/D layout: col = lane&15, row = (lane>>4)*4 + reg
  #pragma unroll
  for (int im=0; im<TM; ++im){
    const int rbase = m0 + wm + im*16 + q*4;
    float rs[4] = {0.f,0.f,0.f,0.f};
    #pragma unroll
    for (int in=0; in<TN; ++in){
      const int col = n0 + wn + in*16 + ln;
      if (EPI == 0){
        #pragma unroll
        for (int r=0; r<4; ++r)
          C[(size_t)(rbase+r)*ldc + col] = acc[im][in][r];
      } else if (EPI == 1){
        float bb = bias[col];
        u16* Cb = (u16*)C;
        #pragma unroll
        for (int r=0; r<4; ++r)
          Cb[(size_t)(rbase+r)*ldc + col] = f2bf(tanhf(acc[im][in][r] + bb));
      } else {
        bool ok = col < nlim;
        #pragma unroll
        for (int r=0; r<4; ++r){
          float e = ok ? __expf(acc[im][in][r]) : 0.f;
          rs[r] += e;
          if (ok) C[(size_t)(rbase+r)*ldc + col] = e;
        }
      }
    }
    if (EPI == 2){
      #pragma unroll
      for (int off=1; off<16; off<<=1){
        rs[0] += __shfl_xor(rs[0], off, 64);
        rs[1] += __shfl_xor(rs[1], off, 64);
        rs[2] += __shfl_xor(rs[2], off, 64);
        rs[3] += __shfl_xor(rs[3], off, 64);
      }
      if (ln == 0){
        #pragma unroll
        for (int r=0; r<4; ++r) atomicAdd(&rowsum[rbase+r], rs[r]);
      }
    }
  }
}

// ---------------------------------------------------------------------------
// fp32 -> bf16 converter (for lstm_r)
// ---------------------------------------------------------------------------
__global__ __launch_bounds__(256)
void cvt_bf16(const float* __restrict__ src, u16* __restrict__ dst){
  int i = (blockIdx.x*256 + threadIdx.x) * 4;
  f4v v = *(const f4v*)(src + i);
  uint2 p;
  p.x = (u32)f2bf(v.x) | ((u32)f2bf(v.y)<<16);
  p.y = (u32)f2bf(v.z) | ((u32)f2bf(v.w)<<16);
  *(uint2*)(dst + i) = p;
}

// ---------------------------------------------------------------------------
// One LSTM step as an MFMA GEMM with fused gates.
// z[32, 2048] = h[32,512] @ Wr[512,2048];  grid 8 blocks, each owns a 64-wide
// j-slice (all 4 gate columns of it): block cols cb = gate*64 + jj,
// global col = gate*512 + j0 + jj.  Epilogue computes c,h for its j-slice.
// Wave w owns jj in [w*16, w*16+16): its 4 gate fragments live in-register,
// so the gate combine is lane-local.
// ---------------------------------------------------------------------------
__global__ __launch_bounds__(256)
void lstm_step_mm(const u16* __restrict__ wr, const float* __restrict__ xk,
                  const float* __restrict__ bias, const float* __restrict__ h_in,
                  float* __restrict__ h_out, float* __restrict__ c_cur,
                  float* __restrict__ hidden, float* __restrict__ out_h,
                  float* __restrict__ out_c, int t)
{
  constexpr int LDT = 36;
  __shared__ u16 Bl[256*LDT];
  __shared__ u16 Al[32*LDT];
  const int tid = threadIdx.x, lane = tid & 63, wave = tid >> 6;
  const int j0 = blockIdx.x * 64;
  const int q = lane >> 4, ln = lane & 15;

  f4v acc[2][4];
  #pragma unroll
  for (int mt=0; mt<2; ++mt)
    #pragma unroll
    for (int g=0; g<4; ++g) acc[mt][g] = 0.f;

  for (int kb=0; kb<16; ++kb){
    __syncthreads();
    { // A: h_in[32][512] tile -> bf16 Al[row][k]   (1024 floats, 1 float4/thread)
      int r = tid >> 3, ck = tid & 7;
      f4v v = *(const f4v*)(h_in + (size_t)r*NH + kb*32 + ck*4);
      uint2 p;
      p.x = (u32)f2bf(v.x) | ((u32)f2bf(v.y)<<16);
      p.y = (u32)f2bf(v.z) | ((u32)f2bf(v.w)<<16);
      *(uint2*)&Al[r*LDT + ck*4] = p;
    }
    // B: wr tile [32 k][4 gates x 64 j] -> Bl[cb][k], u16x8 loads + scatter
    #pragma unroll
    for (int p=0; p<4; ++p){
      int idx = tid + p*256;          // 1024 chunks of 8
      int k = idx >> 5, rem = idx & 31;
      int g = rem >> 3, c8 = rem & 7;
      const u16* src = wr + (size_t)(kb*32+k)*2048 + g*512 + j0 + c8*8;
      uint2 v0 = *(const uint2*)src;
      uint2 v1 = *(const uint2*)(src+4);
      u16 e[8];
      *(uint2*)&e[0] = v0; *(uint2*)&e[4] = v1;
      int cb = g*64 + c8*8;
      #pragma unroll
      for (int j=0; j<8; ++j) Bl[(cb+j)*LDT + k] = e[j];
    }
    __syncthreads();
    s8v af[2], bf[4];
    #pragma unroll
    for (int mt=0; mt<2; ++mt)
      af[mt] = ld_frag(&Al[(mt*16+ln)*LDT + q*8]);
    #pragma unroll
    for (int g=0; g<4; ++g)
      bf[g] = ld_frag(&Bl[(g*64 + wave*16 + ln)*LDT + q*8]);
    #pragma unroll
    for (int mt=0; mt<2; ++mt)
      #pragma unroll
      for (int g=0; g<4; ++g)
        acc[mt][g] = mfma16(af[mt], bf[g], acc[mt][g]);
  }

  const int j = j0 + wave*16 + ln;
  const float bi = bias[j], bfg = bias[NH+j], bg = bias[2*NH+j], bo = bias[3*NH+j];
  #pragma unroll
  for (int mt=0; mt<2; ++mt){
    #pragma unroll
    for (int r=0; r<4; ++r){
      const int b_ = mt*16 + q*4 + r;
      const float* xr = xk + (size_t)(b_*NT+t)*2048;
      float zi = acc[mt][0][r] + xr[j]        + bi;
      float zf = acc[mt][1][r] + xr[NH+j]     + bfg;
      float zg = acc[mt][2][r] + xr[2*NH+j]   + bg;
      float zo = acc[mt][3][r] + xr[3*NH+j]   + bo;
      float c = sigm(zf)*c_cur[(size_t)b_*NH+j] + sigm(zi)*tanhf(zg);
      float h = sigm(zo)*tanhf(c);
      c_cur[(size_t)b_*NH+j] = c;
      h_out[(size_t)b_*NH+j] = h;
      hidden[(size_t)(b_*NT+t)*NH + j] = h;
      if (t == NT-1){ out_h[(size_t)b_*NH+j] = h; out_c[(size_t)b_*NH+j] = c; }
    }
  }
}

// ---------------------------------------------------------------------------
// Attention: scores = q . enc, masked softmax over s, context; writes
// concat[r][0:512]=context, concat[r][512:1024]=hidden.  grid 32 (b), 1024 thr.
// ---------------------------------------------------------------------------
__global__ __launch_bounds__(1024)
void attn_ctx(const float* __restrict__ q, const float* __restrict__ enc,
              const int* __restrict__ enc_len, const float* __restrict__ hidden,
              float* __restrict__ concat)
{
  const int b = blockIdx.x;
  __shared__ float qs[NT][NENC];
  __shared__ float at[NT][NS];
  __shared__ float cred[NT][NENC];
  const int tid = threadIdx.x;
  for (int i=tid; i<NT*NENC; i+=1024) ((float*)qs)[i] = q[(size_t)b*NT*NENC + i];
  __syncthreads();
  const int len = enc_len[b];
  { // scores: thread = (s, t-pair)
    int s = tid & 255, tg = (tid >> 8) * 2;
    const float* er = enc + ((size_t)(b*NS+s))*NENC;
    float s0 = 0.f, s1 = 0.f;
    for (int e=0; e<NENC; e+=4){
      f4v v = *(const f4v*)(er+e);
      s0 += v.x*qs[tg][e]   + v.y*qs[tg][e+1]   + v.z*qs[tg][e+2]   + v.w*qs[tg][e+3];
      s1 += v.x*qs[tg+1][e] + v.y*qs[tg+1][e+1] + v.z*qs[tg+1][e+2] + v.w*qs[tg+1][e+3];
    }
    bool m = s < len;
    at[tg][s]   = m ? s0 : -3.0e38f;
    at[tg+1][s] = m ? s1 : -3.0e38f;
  }
  __syncthreads();
  { // softmax: wave w handles t=w
    int wave = tid >> 6, lane = tid & 63;
    if (wave < NT){
      float v[4]; float mx = -3.0e38f;
      #pragma unroll
      for (int i=0;i<4;++i){ v[i] = at[wave][lane+64*i]; mx = fmaxf(mx, v[i]); }
      #pragma unroll
      for (int off=1; off<64; off<<=1) mx = fmaxf(mx, __shfl_xor(mx, off, 64));
      float sum = 0.f;
      #pragma unroll
      for (int i=0;i<4;++i){ v[i] = __expf(v[i]-mx); sum += v[i]; }
      #pragma unroll
      for (int off=1; off<64; off<<=1) sum += __shfl_xor(sum, off, 64);
      float inv = 1.f/sum;
      #pragma unroll
      for (int i=0;i<4;++i) at[wave][lane+64*i] = v[i]*inv;
    }
  }
  __syncthreads();
  { // context: thread = (e, s-half)
    int e = tid & 511, sh = tid >> 9;
    float cx[NT];
    #pragma unroll
    for (int t=0;t<NT;++t) cx[t] = 0.f;
    for (int si=0; si<128; ++si){
      int s = sh*128 + si;
      float v = enc[((size_t)(b*NS+s))*NENC + e];
      #pragma unroll
      for (int t=0;t<NT;++t) cx[t] += at[t][s]*v;
    }
    if (sh == 1){
      #pragma unroll
      for (int t=0;t<NT;++t) cred[t][e] = cx[t];
    }
    __syncthreads();
    if (sh == 0){
      #pragma unroll
      for (int t=0;t<NT;++t)
        concat[(size_t)(b*NT+t)*1024 + e] = cx[t] + cred[t][e];
    } else {
      #pragma unroll
      for (int t=0;t<NT;++t)
        concat[(size_t)(b*NT+t)*1024 + 512 + e] = hidden[(size_t)(b*NT+t)*NH + e];
    }
  }
}

// ---------------------------------------------------------------------------
// OOV region fill: total[r][50000:51000] = 1e-10
// ---------------------------------------------------------------------------
__global__ __launch_bounds__(256)
void oov_fill(float* __restrict__ outp){
  float* p = outp + (size_t)blockIdx.x*NVT + NVOC;
  for (int i=threadIdx.x; i<1000; i+=256) p[i] = 1e-10f;
}

// ---------------------------------------------------------------------------
// cs = exp(attn_out @ copy_k^T) with mask; scatter-add into extended vocab
// + rowsum atomics.  MFMA 16x16x32, M=8 padded to 16. grid 128 = (b, sblk).
// ---------------------------------------------------------------------------
__global__ __launch_bounds__(256)
void cs_scatter(const u16* __restrict__ attn_bf, const u16* __restrict__ copy_k,
                const int* __restrict__ enc_x, const int* __restrict__ enc_len,
                float* __restrict__ outp, float* __restrict__ rowsum)
{
  const int b  = blockIdx.x >> 2;
  const int sb = blockIdx.x & 3;
  __shared__ u16 Al[16*520];
  const int tid = threadIdx.x;
  for (int i=tid; i<16*64; i+=256){      // 1024 chunks of 8 shorts
    int row = i >> 6, ck = i & 63;
    uint2 v0 = {0u,0u}, v1 = {0u,0u};
    if (row < NT){
      const u16* s = attn_bf + ((size_t)(b*NT+row))*NH + ck*8;
      v0 = *(const uint2*)s; v1 = *(const uint2*)(s+4);
    }
    u16* d = &Al[row*520 + ck*8];
    *(uint2*)d = v0; *(uint2*)(d+4) = v1;
  }
  __syncthreads();
  const int wave = tid >> 6, lane = tid & 63;
  const int q = lane >> 4, ln = lane & 15;
  const int s0 = sb*64 + wave*16;
  f4v acc = 0.f;
  const u16* Bg = copy_k + ((size_t)(b*NS + s0 + ln))*NH;
  for (int kb=0; kb<16; ++kb){
    s8v a = ld_frag(&Al[ln*520 + kb*32 + q*8]);
    s8v bb = ld_frag(Bg + kb*32 + q*8);
    acc = mfma16(a, bb, acc);
  }
  const int s = s0 + ln;
  const int len = enc_len[b];
  const int vidx = enc_x[b*NS + s];
  const bool valid = (s < len);
  float rs[4];
  #pragma unroll
  for (int r=0; r<4; ++r){
    int t = q*4 + r;
    float e = (valid && t < NT) ? __expf(acc[r]) : 0.f;
    rs[r] = e;
    if (e != 0.f) atomicAdd(&outp[(size_t)(b*NT+t)*NVT + vidx], e);
  }
  #pragma unroll
  for (int off=1; off<16; off<<=1){
    rs[0] += __shfl_xor(rs[0], off, 64);
    rs[1] += __shfl_xor(rs[1], off, 64);
    rs[2] += __shfl_xor(rs[2], off, 64);
    rs[3] += __shfl_xor(rs[3], off, 64);
  }
  if (ln == 0){
    #pragma unroll
    for (int r=0; r<4; ++r){
      int t = q*4 + r;
      if (t < NT) atomicAdd(&rowsum[b*NT+t], rs[r]);
    }
  }
}

// ---------------------------------------------------------------------------
// rowsum -> log(rowsum + 1000*1e-10) in place (256 rows)
// ---------------------------------------------------------------------------
__global__ void log_rowsum(float* rowsum){
  int i = threadIdx.x;
  rowsum[i] = __logf(rowsum[i] + 1e-7f);
}

// ---------------------------------------------------------------------------
// out = log(total) - logsum[row]; 2D grid (f4-chunk, row)
// ---------------------------------------------------------------------------
__global__ __launch_bounds__(256)
void norm_log(float* __restrict__ outp, const float* __restrict__ logsum){
  const int i4 = blockIdx.x*256 + threadIdx.x;   // 0..12749 per row
  if (i4 >= 12750) return;
  const int r = blockIdx.y;
  const float ls = logsum[r];
  float* p = outp + (size_t)r*NVT + i4*4;
  f4v v = *(const f4v*)p;
  v.x = __logf(v.x) - ls;
  v.y = __logf(v.y) - ls;
  v.z = __logf(v.z) - ls;
  v.w = __logf(v.w) - ls;
  *(f4v*)p = v;
}

// ---------------------------------------------------------------------------
extern "C" void kernel_launch(void* const* d_in, const int* in_sizes, int n_in,
                              void* d_out, int out_size, void* d_ws, size_t ws_size,
                              hipStream_t stream)
{
  (void)in_sizes; (void)n_in; (void)out_size; (void)ws_size;
  const int*   dec_x      = (const int*)  d_in[0];
  const int*   enc_x      = (const int*)  d_in[1];
  const int*   enc_len    = (const int*)  d_in[2];
  const float* enc_output = (const float*)d_in[3];
  const float* enc_h      = (const float*)d_in[4];
  const float* enc_c      = (const float*)d_in[5];
  const float* embedding  = (const float*)d_in[8];
  const float* lstm_k     = (const float*)d_in[9];
  const float* lstm_r     = (const float*)d_in[10];
  const float* lstm_b     = (const float*)d_in[11];
  const float* attn_w     = (const float*)d_in[12];
  const float* out_w      = (const float*)d_in[13];
  const float* out_b      = (const float*)d_in[14];
  const float* gen_w      = (const float*)d_in[15];
  const float* copy_w     = (const float*)d_in[16];
  const float* copy_b     = (const float*)d_in[17];

  float* outp  = (float*)d_out;
  float* out_h = outp + (size_t)NB*NT*NVT;       // 13,056,000
  float* out_c = out_h + NB*NH;

  char* ws = (char*)d_ws;
  u16*   wr_bf   = (u16*)ws;    ws += (size_t)NH*2048*2;      // 2 MB
  float* xk      = (float*)ws;  ws += (size_t)NB*NT*2048*4;   // 2 MB
  float* hbuf0   = (float*)ws;  ws += NB*NH*4;
  float* hbuf1   = (float*)ws;  ws += NB*NH*4;
  float* c_cur   = (float*)ws;  ws += NB*NH*4;
  float* hidden  = (float*)ws;  ws += (size_t)NB*NT*NH*4;     // 512 KB
  float* qbuf    = (float*)ws;  ws += (size_t)NB*NT*NENC*4;   // 512 KB
  float* concat  = (float*)ws;  ws += (size_t)NB*NT*1024*4;   // 1 MB
  u16*   attn_bf = (u16*)ws;    ws += (size_t)NB*NT*NH*2;     // 256 KB
  u16*   copy_k  = (u16*)ws;    ws += (size_t)NB*NS*NH*2;     // 8 MB
  float* rowsum  = (float*)ws;  ws += NB*NT*4;

  hipMemsetAsync(rowsum, 0, NB*NT*4, stream);
  cvt_bf16<<<1024,256,0,stream>>>(lstm_r, wr_bf);             // 512*2048 / 1024

  // xk = embedding[dec_x] @ lstm_k   (M=256, K=256, N=2048) — m fastest
  gemm_mfma<64,64,0,false,true,true><<<dim3(4,32),256,0,stream>>>(
      embedding, lstm_k, xk, dec_x, nullptr, nullptr, 256, NEMB, 2048, 2048, 2048);

  hipMemcpyAsync(hbuf0, enc_h, NB*NH*4, hipMemcpyDeviceToDevice, stream);
  hipMemcpyAsync(c_cur, enc_c, NB*NH*4, hipMemcpyDeviceToDevice, stream);

  float* hb[2] = {hbuf0, hbuf1};
  for (int t=0; t<NT; ++t)
    lstm_step_mm<<<8,256,0,stream>>>(wr_bf, xk, lstm_b, hb[t&1], hb[(t+1)&1],
                                     c_cur, hidden, out_h, out_c, t);

  // q = hidden @ attn_w  (M=256, K=512, N=512) — m fastest
  gemm_mfma<64,64,0,false,false,true><<<dim3(4,8),256,0,stream>>>(
      hidden, attn_w, qbuf, nullptr, nullptr, nullptr, NH, NH, NENC, NENC, NENC);

  attn_ctx<<<32,1024,0,stream>>>(qbuf, enc_output, enc_len, hidden, concat);

  // attn_out = tanh(concat @ out_w + out_b) -> bf16  (M=256, K=1024, N=512)
  gemm_mfma<64,64,1,false,false,true><<<dim3(4,8),256,0,stream>>>(
      concat, out_w, (float*)attn_bf, nullptr, out_b, nullptr, 1024, 1024, NH, NH, NH);

  // copy_k = tanh(enc_output @ copy_w + copy_b) -> bf16 (M=8192, K=512, N=512)
  // n fastest so enc_output streams once (A-tile reused in L2 across n-blocks)
  gemm_mfma<128,128,1,false,false,false><<<dim3(4,64),256,0,stream>>>(
      enc_output, copy_w, (float*)copy_k, nullptr, copy_b, nullptr, NENC, NENC, NH, NH, NH);

  // gen = exp(attn_out @ gen_w) -> out + row sums (M=256, K=512, N=50000)
  // m fastest: the 2 m-blocks of a given n share the B tile via L2
  gemm_mfma<128,64,2,true,false,true><<<dim3(2,782),256,0,stream>>>(
      attn_bf, gen_w, outp, nullptr, nullptr, rowsum, NH, NH, NVOC, NVT, NVOC);

  oov_fill<<<NB*NT,256,0,stream>>>(outp);
  cs_scatter<<<128,256,0,stream>>>(attn_bf, copy_k, enc_x, enc_len, outp, rowsum);
  log_rowsum<<<1,NB*NT,0,stream>>>(rowsum);
  norm_log<<<dim3(50,NB*NT),256,0,stream>>>(outp, rowsum);
}

// Round 3
// 605.900 us; speedup vs baseline: 1.6232x; 1.6232x over previous
//
#include <hip/hip_runtime.h>
#include <hip/hip_bf16.h>

typedef unsigned short u16;
typedef unsigned int   u32;
typedef __attribute__((ext_vector_type(4))) float f4v;
typedef __attribute__((ext_vector_type(8))) short s8v;
typedef __attribute__((ext_vector_type(4))) unsigned int u4v;

#define NB   32      // batch
#define NS   256     // src len
#define NT   8       // dec len
#define NH   512     // hidden
#define NENC 512
#define NEMB 256
#define NVOC 50000
#define NVT  51000

__device__ __forceinline__ float bf2f(u16 u){ return __uint_as_float(((u32)u)<<16); }
__device__ __forceinline__ u16 f2bf(float f){
  u32 x = __float_as_uint(f);
  return (u16)((x + 0x7fffu + ((x>>16)&1u)) >> 16);   // RNE
}
__device__ __forceinline__ s8v ld_frag16(const u16* p){
  union{ s8v v; u4v u; } t;
  t.u = *(const u4v*)p;
  return t.v;
}
__device__ __forceinline__ f4v mfma16(s8v a, s8v b, f4v c){
  return __builtin_amdgcn_mfma_f32_16x16x32_bf16(a,b,c,0,0,0);
}
__device__ __forceinline__ float sigm(float x){ return 1.f/(1.f+__expf(-x)); }

// ---------------------------------------------------------------------------
// Transpose+convert: in [K][N] fp32 -> out [N][K] bf16.  32x32 tiles via LDS.
// grid (ceil(N/32), K/32), block 256.
// ---------------------------------------------------------------------------
__global__ __launch_bounds__(256)
void transpose_cvt(const float* __restrict__ in, u16* __restrict__ out,
                   int K, int N)
{
  __shared__ u16 tile[32*40];
  const int n0 = blockIdx.x*32, k0 = blockIdx.y*32;
  const int tid = threadIdx.x;
  { // load 32 k-rows x 32 n-cols, convert, store [k][n] in LDS
    int r = tid>>3, c4 = tid&7;
    int c = n0 + c4*4;
    if (c+4 > N) c = N-4;
    f4v v = *(const f4v*)(in + (size_t)(k0+r)*N + c);
    uint2 p;
    p.x = (u32)f2bf(v.x) | ((u32)f2bf(v.y)<<16);
    p.y = (u32)f2bf(v.z) | ((u32)f2bf(v.w)<<16);
    *(uint2*)&tile[r*40 + c4*4] = p;
  }
  __syncthreads();
  { // write 32 n-rows x 32 k each (uint2 = 4 bf16 per thread)
    int r2 = tid>>3, kc = tid&7;
    int n = n0 + r2;
    if (n < N){
      u16 e[4];
      #pragma unroll
      for (int j=0; j<4; ++j) e[j] = tile[(kc*4+j)*40 + r2];
      *(uint2*)(out + (size_t)n*K + k0 + kc*4) = *(uint2*)e;
    }
  }
}

// ---------------------------------------------------------------------------
// fp32 -> bf16 converter (grid*256*4 elements)
// ---------------------------------------------------------------------------
__global__ __launch_bounds__(256)
void cvt_bf16(const float* __restrict__ src, u16* __restrict__ dst){
  int i = (blockIdx.x*256 + threadIdx.x) * 4;
  f4v v = *(const f4v*)(src + i);
  uint2 p;
  p.x = (u32)f2bf(v.x) | ((u32)f2bf(v.y)<<16);
  p.y = (u32)f2bf(v.z) | ((u32)f2bf(v.w)<<16);
  *(uint2*)(dst + i) = p;
}

// ---------------------------------------------------------------------------
// Tiled bf16-MFMA GEMM, B pre-transposed: C[M,N] = epi(A[M,K] @ Bt[N,K]^T)
//   A: fp32 (inline convert, optional row-gather) or bf16 direct
//   Bt: bf16 [N][K] row-major -> staged with pure 16B copies (no transpose)
//   EPI 0: fp32 store   1: bf16 store of tanh(x+bias[n])
//   EPI 2: fp32 store of exp(x) for n<nlim + atomic per-row sums
//   MXA:  true -> m0 from blockIdx.x (m fastest)
// Block 256 = 4 waves (2x2), wave tile (BM/2)x(BN/2), 16x16x32 MFMA.
// LDS row stride 40 u16 (80B): 16B-aligned b128 frags, ~2-way banks (free).
// ---------------------------------------------------------------------------
template<int BM, int BN, int EPI, bool ABF16, bool AGATHER, bool MXA>
__global__ __launch_bounds__(256)
void gemm_bt(const void* __restrict__ Av, const u16* __restrict__ Bt,
             float* __restrict__ C, const int* __restrict__ a_idx,
             const float* __restrict__ bias, float* __restrict__ rowsum,
             int K, int lda, int ldc, int nlim)
{
  constexpr int LDT = 40;
  __shared__ u16 Al[BM*LDT];
  __shared__ u16 Bl[BN*LDT];
  const int tid  = threadIdx.x;
  const int lane = tid & 63;
  const int wave = tid >> 6;
  const int m0 = (MXA ? blockIdx.x : blockIdx.y) * BM;
  const int n0 = (MXA ? blockIdx.y : blockIdx.x) * BN;
  constexpr int TM = BM/32;
  constexpr int TN = BN/32;
  const int wm = (wave>>1)*(BM/2);
  const int wn = (wave&1)*(BN/2);
  const int q  = lane >> 4;
  const int ln = lane & 15;

  f4v acc[TM][TN];
  #pragma unroll
  for (int im=0; im<TM; ++im)
    #pragma unroll
    for (int in=0; in<TN; ++in) acc[im][in] = 0.f;

  const int KB = K >> 5;
  for (int kb=0; kb<KB; ++kb){
    __syncthreads();
    // ---- stage A tile [BM x 32k] -> Al
    if (ABF16){
      const u16* Ag = (const u16*)Av;
      #pragma unroll
      for (int p=0; p<BM/64; ++p){
        int el = tid + p*256;
        int row = el>>2, ck = el&3;
        *(u4v*)&Al[row*LDT + ck*8] =
            *(const u4v*)(Ag + (size_t)(m0+row)*lda + kb*32 + ck*8);
      }
    } else {
      const float* Ag = (const float*)Av;
      #pragma unroll
      for (int p=0; p<BM/32; ++p){
        int el = tid + p*256;
        int row = el>>3, ck = el&7;
        int grow = AGATHER ? a_idx[m0+row] : (m0+row);
        f4v v = *(const f4v*)(Ag + (size_t)grow*lda + kb*32 + ck*4);
        uint2 pk;
        pk.x = (u32)f2bf(v.x) | ((u32)f2bf(v.y)<<16);
        pk.y = (u32)f2bf(v.z) | ((u32)f2bf(v.w)<<16);
        *(uint2*)&Al[row*LDT + ck*4] = pk;
      }
    }
    // ---- stage B tile [BN rows x 32k] -> Bl (straight 16B copies)
    #pragma unroll
    for (int p=0; p<BN/64; ++p){
      int el = tid + p*256;
      int row = el>>2, ck = el&3;
      int nr = n0 + row; if (nr >= nlim) nr = nlim-1;
      *(u4v*)&Bl[row*LDT + ck*8] =
          *(const u4v*)(Bt + (size_t)nr*K + kb*32 + ck*8);
    }
    __syncthreads();
    // ---- fragments + MFMA
    s8v af[TM], bfr[TN];
    #pragma unroll
    for (int im=0; im<TM; ++im)
      af[im] = ld_frag16(&Al[(wm+im*16+ln)*LDT + q*8]);
    #pragma unroll
    for (int in=0; in<TN; ++in)
      bfr[in] = ld_frag16(&Bl[(wn+in*16+ln)*LDT + q*8]);
    #pragma unroll
    for (int im=0; im<TM; ++im)
      #pragma unroll
      for (int in=0; in<TN; ++in)
        acc[im][in] = mfma16(af[im], bfr[in], acc[im][in]);
  }

  // ---- epilogue. C/D layout: col = lane&15, row = (lane>>4)*4 + reg
  #pragma unroll
  for (int im=0; im<TM; ++im){
    const int rbase = m0 + wm + im*16 + q*4;
    float rs[4] = {0.f,0.f,0.f,0.f};
    #pragma unroll
    for (int in=0; in<TN; ++in){
      const int col = n0 + wn + in*16 + ln;
      if (EPI == 0){
        #pragma unroll
        for (int r=0; r<4; ++r)
          C[(size_t)(rbase+r)*ldc + col] = acc[im][in][r];
      } else if (EPI == 1){
        float bb = bias[col];
        u16* Cb = (u16*)C;
        #pragma unroll
        for (int r=0; r<4; ++r)
          Cb[(size_t)(rbase+r)*ldc + col] = f2bf(tanhf(acc[im][in][r] + bb));
      } else {
        bool ok = col < nlim;
        #pragma unroll
        for (int r=0; r<4; ++r){
          float e = ok ? __expf(acc[im][in][r]) : 0.f;
          rs[r] += e;
          if (ok) C[(size_t)(rbase+r)*ldc + col] = e;
        }
      }
    }
    if (EPI == 2){
      #pragma unroll
      for (int off=1; off<16; off<<=1){
        rs[0] += __shfl_xor(rs[0], off, 64);
        rs[1] += __shfl_xor(rs[1], off, 64);
        rs[2] += __shfl_xor(rs[2], off, 64);
        rs[3] += __shfl_xor(rs[3], off, 64);
      }
      if (ln == 0){
        #pragma unroll
        for (int r=0; r<4; ++r) atomicAdd(&rowsum[rbase+r], rs[r]);
      }
    }
  }
}

// ---------------------------------------------------------------------------
// One LSTM step. grid 32 (j-slices of 16), block 256 = 4 waves (one per gate).
// Fragments load DIRECTLY from global (wrT bf16 [2048][512], h bf16 [32][512])
// — no LDS / no barrier in the K-loop. Gate-combine via one LDS exchange.
// ---------------------------------------------------------------------------
__global__ __launch_bounds__(256)
void lstm_step2(const u16* __restrict__ wrT, const float* __restrict__ xk,
                const float* __restrict__ bias, const u16* __restrict__ hb_in,
                u16* __restrict__ hb_out, float* __restrict__ c_cur,
                float* __restrict__ hidden, float* __restrict__ out_h,
                float* __restrict__ out_c, int t)
{
  const int tid = threadIdx.x, lane = tid & 63, g = tid >> 6;
  const int q = lane >> 4, ln = lane & 15;
  const int j0 = blockIdx.x * 16;

  f4v acc0 = 0.f, acc1 = 0.f;
  const u16* bp = wrT + (size_t)(g*NH + j0 + ln)*NH;
  const u16* a0 = hb_in + (size_t)ln*NH;
  const u16* a1 = hb_in + (size_t)(16+ln)*NH;
  #pragma unroll 4
  for (int kb=0; kb<16; ++kb){
    s8v bf  = ld_frag16(bp + kb*32 + q*8);
    s8v af0 = ld_frag16(a0 + kb*32 + q*8);
    s8v af1 = ld_frag16(a1 + kb*32 + q*8);
    acc0 = mfma16(af0, bf, acc0);
    acc1 = mfma16(af1, bf, acc1);
  }

  __shared__ float zs[4][32][17];
  #pragma unroll
  for (int r=0; r<4; ++r){
    zs[g][q*4+r][ln]    = acc0[r];
    zs[g][16+q*4+r][ln] = acc1[r];
  }
  __syncthreads();

  #pragma unroll
  for (int pp=0; pp<2; ++pp){
    int pair = tid + pp*256;
    int b = pair >> 4, jj = pair & 15;
    int j = j0 + jj;
    const float* xr = xk + (size_t)(b*NT+t)*2048;
    float zi = zs[0][b][jj] + xr[j]        + bias[j];
    float zf = zs[1][b][jj] + xr[NH+j]     + bias[NH+j];
    float zg = zs[2][b][jj] + xr[2*NH+j]   + bias[2*NH+j];
    float zo = zs[3][b][jj] + xr[3*NH+j]   + bias[3*NH+j];
    float c = sigm(zf)*c_cur[(size_t)b*NH+j] + sigm(zi)*tanhf(zg);
    float h = sigm(zo)*tanhf(c);
    c_cur[(size_t)b*NH+j] = c;
    hb_out[(size_t)b*NH+j] = f2bf(h);
    hidden[(size_t)(b*NT+t)*NH + j] = h;
    if (t == NT-1){ out_h[(size_t)b*NH+j] = h; out_c[(size_t)b*NH+j] = c; }
  }
}

// ---------------------------------------------------------------------------
// Attention: scores = q . enc, masked softmax over s, context; writes
// concat[r][0:512]=context, concat[r][512:1024]=hidden.  grid 32 (b), 1024 thr.
// ---------------------------------------------------------------------------
__global__ __launch_bounds__(1024)
void attn_ctx(const float* __restrict__ q, const float* __restrict__ enc,
              const int* __restrict__ enc_len, const float* __restrict__ hidden,
              float* __restrict__ concat)
{
  const int b = blockIdx.x;
  __shared__ float qs[NT][NENC];
  __shared__ float at[NT][NS];
  __shared__ float cred[NT][NENC];
  const int tid = threadIdx.x;
  for (int i=tid; i<NT*NENC; i+=1024) ((float*)qs)[i] = q[(size_t)b*NT*NENC + i];
  __syncthreads();
  const int len = enc_len[b];
  { // scores: thread = (s, t-pair)
    int s = tid & 255, tg = (tid >> 8) * 2;
    const float* er = enc + ((size_t)(b*NS+s))*NENC;
    float s0 = 0.f, s1 = 0.f;
    for (int e=0; e<NENC; e+=4){
      f4v v = *(const f4v*)(er+e);
      s0 += v.x*qs[tg][e]   + v.y*qs[tg][e+1]   + v.z*qs[tg][e+2]   + v.w*qs[tg][e+3];
      s1 += v.x*qs[tg+1][e] + v.y*qs[tg+1][e+1] + v.z*qs[tg+1][e+2] + v.w*qs[tg+1][e+3];
    }
    bool m = s < len;
    at[tg][s]   = m ? s0 : -3.0e38f;
    at[tg+1][s] = m ? s1 : -3.0e38f;
  }
  __syncthreads();
  { // softmax: wave w handles t=w
    int wave = tid >> 6, lane = tid & 63;
    if (wave < NT){
      float v[4]; float mx = -3.0e38f;
      #pragma unroll
      for (int i=0;i<4;++i){ v[i] = at[wave][lane+64*i]; mx = fmaxf(mx, v[i]); }
      #pragma unroll
      for (int off=1; off<64; off<<=1) mx = fmaxf(mx, __shfl_xor(mx, off, 64));
      float sum = 0.f;
      #pragma unroll
      for (int i=0;i<4;++i){ v[i] = __expf(v[i]-mx); sum += v[i]; }
      #pragma unroll
      for (int off=1; off<64; off<<=1) sum += __shfl_xor(sum, off, 64);
      float inv = 1.f/sum;
      #pragma unroll
      for (int i=0;i<4;++i) at[wave][lane+64*i] = v[i]*inv;
    }
  }
  __syncthreads();
  { // context: thread = (e, s-half)
    int e = tid & 511, sh = tid >> 9;
    float cx[NT];
    #pragma unroll
    for (int t=0;t<NT;++t) cx[t] = 0.f;
    for (int si=0; si<128; ++si){
      int s = sh*128 + si;
      float v = enc[((size_t)(b*NS+s))*NENC + e];
      #pragma unroll
      for (int t=0;t<NT;++t) cx[t] += at[t][s]*v;
    }
    if (sh == 1){
      #pragma unroll
      for (int t=0;t<NT;++t) cred[t][e] = cx[t];
    }
    __syncthreads();
    if (sh == 0){
      #pragma unroll
      for (int t=0;t<NT;++t)
        concat[(size_t)(b*NT+t)*1024 + e] = cx[t] + cred[t][e];
    } else {
      #pragma unroll
      for (int t=0;t<NT;++t)
        concat[(size_t)(b*NT+t)*1024 + 512 + e] = hidden[(size_t)(b*NT+t)*NH + e];
    }
  }
}

// ---------------------------------------------------------------------------
// OOV region fill: total[r][50000:51000] = 1e-10
// ---------------------------------------------------------------------------
__global__ __launch_bounds__(256)
void oov_fill(float* __restrict__ outp){
  float* p = outp + (size_t)blockIdx.x*NVT + NVOC;
  for (int i=threadIdx.x; i<1000; i+=256) p[i] = 1e-10f;
}

// ---------------------------------------------------------------------------
// cs = exp(attn_out @ copy_k^T) with mask; scatter-add into extended vocab
// + rowsum atomics.  MFMA 16x16x32, M=8 padded to 16. grid 128 = (b, sblk).
// ---------------------------------------------------------------------------
__global__ __launch_bounds__(256)
void cs_scatter(const u16* __restrict__ attn_bf, const u16* __restrict__ copy_k,
                const int* __restrict__ enc_x, const int* __restrict__ enc_len,
                float* __restrict__ outp, float* __restrict__ rowsum)
{
  const int b  = blockIdx.x >> 2;
  const int sb = blockIdx.x & 3;
  __shared__ u16 Al[16*520];
  const int tid = threadIdx.x;
  for (int i=tid; i<16*64; i+=256){      // 1024 chunks of 8 shorts
    int row = i >> 6, ck = i & 63;
    uint2 v0 = {0u,0u}, v1 = {0u,0u};
    if (row < NT){
      const u16* s = attn_bf + ((size_t)(b*NT+row))*NH + ck*8;
      v0 = *(const uint2*)s; v1 = *(const uint2*)(s+4);
    }
    u16* d = &Al[row*520 + ck*8];
    *(uint2*)d = v0; *(uint2*)(d+4) = v1;
  }
  __syncthreads();
  const int wave = tid >> 6, lane = tid & 63;
  const int q = lane >> 4, ln = lane & 15;
  const int s0 = sb*64 + wave*16;
  f4v acc = 0.f;
  const u16* Bg = copy_k + ((size_t)(b*NS + s0 + ln))*NH;
  for (int kb=0; kb<16; ++kb){
    s8v a  = ld_frag16(&Al[ln*520 + kb*32 + q*8]);
    s8v bb = ld_frag16(Bg + kb*32 + q*8);
    acc = mfma16(a, bb, acc);
  }
  const int s = s0 + ln;
  const int len = enc_len[b];
  const int vidx = enc_x[b*NS + s];
  const bool valid = (s < len);
  float rs[4];
  #pragma unroll
  for (int r=0; r<4; ++r){
    int t = q*4 + r;
    float e = (valid && t < NT) ? __expf(acc[r]) : 0.f;
    rs[r] = e;
    if (e != 0.f) atomicAdd(&outp[(size_t)(b*NT+t)*NVT + vidx], e);
  }
  #pragma unroll
  for (int off=1; off<16; off<<=1){
    rs[0] += __shfl_xor(rs[0], off, 64);
    rs[1] += __shfl_xor(rs[1], off, 64);
    rs[2] += __shfl_xor(rs[2], off, 64);
    rs[3] += __shfl_xor(rs[3], off, 64);
  }
  if (ln == 0){
    #pragma unroll
    for (int r=0; r<4; ++r){
      int t = q*4 + r;
      if (t < NT) atomicAdd(&rowsum[b*NT+t], rs[r]);
    }
  }
}

// ---------------------------------------------------------------------------
// rowsum -> log(rowsum + 1000*1e-10) in place (256 rows)
// ---------------------------------------------------------------------------
__global__ void log_rowsum(float* rowsum){
  int i = threadIdx.x;
  rowsum[i] = __logf(rowsum[i] + 1e-7f);
}

// ---------------------------------------------------------------------------
// out = log(total) - logsum[row]; 2D grid (f4-chunk, row)
// ---------------------------------------------------------------------------
__global__ __launch_bounds__(256)
void norm_log(float* __restrict__ outp, const float* __restrict__ logsum){
  const int i4 = blockIdx.x*256 + threadIdx.x;   // 0..12749 per row
  if (i4 >= 12750) return;
  const int r = blockIdx.y;
  const float ls = logsum[r];
  float* p = outp + (size_t)r*NVT + i4*4;
  f4v v = *(const f4v*)p;
  v.x = __logf(v.x) - ls;
  v.y = __logf(v.y) - ls;
  v.z = __logf(v.z) - ls;
  v.w = __logf(v.w) - ls;
  *(f4v*)p = v;
}

// ---------------------------------------------------------------------------
extern "C" void kernel_launch(void* const* d_in, const int* in_sizes, int n_in,
                              void* d_out, int out_size, void* d_ws, size_t ws_size,
                              hipStream_t stream)
{
  (void)in_sizes; (void)n_in; (void)out_size; (void)ws_size;
  const int*   dec_x      = (const int*)  d_in[0];
  const int*   enc_x      = (const int*)  d_in[1];
  const int*   enc_len    = (const int*)  d_in[2];
  const float* enc_output = (const float*)d_in[3];
  const float* enc_h      = (const float*)d_in[4];
  const float* enc_c      = (const float*)d_in[5];
  const float* embedding  = (const float*)d_in[8];
  const float* lstm_k     = (const float*)d_in[9];
  const float* lstm_r     = (const float*)d_in[10];
  const float* lstm_b     = (const float*)d_in[11];
  const float* attn_w     = (const float*)d_in[12];
  const float* out_w      = (const float*)d_in[13];
  const float* out_b      = (const float*)d_in[14];
  const float* gen_w      = (const float*)d_in[15];
  const float* copy_w     = (const float*)d_in[16];
  const float* copy_b     = (const float*)d_in[17];

  float* outp  = (float*)d_out;
  float* out_h = outp + (size_t)NB*NT*NVT;       // 13,056,000
  float* out_c = out_h + NB*NH;

  char* ws = (char*)d_ws;
  u16*   genT    = (u16*)ws;    ws += (size_t)NVOC*NH*2;      // 51.2 MB
  u16*   wrT     = (u16*)ws;    ws += (size_t)2048*NH*2;      // 2 MB
  u16*   lstmkT  = (u16*)ws;    ws += (size_t)2048*NEMB*2;    // 1 MB
  u16*   attnT   = (u16*)ws;    ws += (size_t)NENC*NH*2;      // 512 KB
  u16*   outT    = (u16*)ws;    ws += (size_t)NH*1024*2;      // 1 MB
  u16*   copyT   = (u16*)ws;    ws += (size_t)NH*NENC*2;      // 512 KB
  float* xk      = (float*)ws;  ws += (size_t)NB*NT*2048*4;   // 2 MB
  u16*   hb0     = (u16*)ws;    ws += (size_t)NB*NH*2;
  u16*   hb1     = (u16*)ws;    ws += (size_t)NB*NH*2;
  float* c_cur   = (float*)ws;  ws += (size_t)NB*NH*4;
  float* hidden  = (float*)ws;  ws += (size_t)NB*NT*NH*4;     // 512 KB
  float* qbuf    = (float*)ws;  ws += (size_t)NB*NT*NENC*4;   // 512 KB
  float* concat  = (float*)ws;  ws += (size_t)NB*NT*1024*4;   // 1 MB
  u16*   attn_bf = (u16*)ws;    ws += (size_t)NB*NT*NH*2;     // 256 KB
  u16*   copy_k  = (u16*)ws;    ws += (size_t)NB*NS*NH*2;     // 8 MB
  float* rowsum  = (float*)ws;  ws += NB*NT*4;

  hipMemsetAsync(rowsum, 0, NB*NT*4, stream);

  // ---- one-time layout conversions (bf16, [N][K])
  transpose_cvt<<<dim3(1563,16),256,0,stream>>>(gen_w,  genT,   NH,  NVOC);
  transpose_cvt<<<dim3(64,16), 256,0,stream>>>(lstm_r, wrT,    NH,  2048);
  transpose_cvt<<<dim3(64,8),  256,0,stream>>>(lstm_k, lstmkT, NEMB,2048);
  transpose_cvt<<<dim3(16,16), 256,0,stream>>>(attn_w, attnT,  NH,  NENC);
  transpose_cvt<<<dim3(16,32), 256,0,stream>>>(out_w,  outT,   1024,NH);
  transpose_cvt<<<dim3(16,16), 256,0,stream>>>(copy_w, copyT,  NENC,NH);
  cvt_bf16<<<16,256,0,stream>>>(enc_h, hb0);
  hipMemcpyAsync(c_cur, enc_c, NB*NH*4, hipMemcpyDeviceToDevice, stream);

  // copy_k = tanh(enc_output @ copy_w + copy_b) -> bf16 (M=8192, K=512, N=512)
  gemm_bt<128,128,1,false,false,false><<<dim3(4,64),256,0,stream>>>(
      enc_output, copyT, (float*)copy_k, nullptr, copy_b, nullptr, NENC, NENC, NH, NH);

  // xk = embedding[dec_x] @ lstm_k   (M=256, K=256, N=2048)
  gemm_bt<64,64,0,false,true,true><<<dim3(4,32),256,0,stream>>>(
      embedding, lstmkT, xk, dec_x, nullptr, nullptr, NEMB, NEMB, 2048, 2048);

  u16* hb[2] = {hb0, hb1};
  for (int t=0; t<NT; ++t)
    lstm_step2<<<32,256,0,stream>>>(wrT, xk, lstm_b, hb[t&1], hb[(t+1)&1],
                                    c_cur, hidden, out_h, out_c, t);

  // q = hidden @ attn_w  (M=256, K=512, N=512)
  gemm_bt<64,64,0,false,false,true><<<dim3(4,8),256,0,stream>>>(
      hidden, attnT, qbuf, nullptr, nullptr, nullptr, NH, NH, NENC, NENC);

  attn_ctx<<<32,1024,0,stream>>>(qbuf, enc_output, enc_len, hidden, concat);

  // attn_out = tanh(concat @ out_w + out_b) -> bf16  (M=256, K=1024, N=512)
  gemm_bt<64,64,1,false,false,true><<<dim3(4,8),256,0,stream>>>(
      concat, outT, (float*)attn_bf, nullptr, out_b, nullptr, 1024, 1024, NH, NH);

  // gen = exp(attn_out @ gen_w) -> out + row sums (M=256, K=512, N=50000)
  gemm_bt<128,128,2,true,false,true><<<dim3(2,391),256,0,stream>>>(
      attn_bf, genT, outp, nullptr, nullptr, rowsum, NH, NH, NVT, NVOC);

  oov_fill<<<NB*NT,256,0,stream>>>(outp);
  cs_scatter<<<128,256,0,stream>>>(attn_bf, copy_k, enc_x, enc_len, outp, rowsum);
  log_rowsum<<<1,NB*NT,0,stream>>>(rowsum);
  norm_log<<<dim3(50,NB*NT),256,0,stream>>>(outp, rowsum);
}